// Round 1
// baseline (8499.332 us; speedup 1.0000x reference)
//
#include <hip/hip_runtime.h>
#include <stdint.h>

// MinGRU persistent kernel for MI355X (gfx950).
// B=128, T=1024, I=256, H=512.
// 8 clusters x 8 WGs; cluster = blockIdx%8 (XCD affinity heuristic).
// Each WG: 512 threads = 8 waves; wave w<4 -> z-tile w, wave>=4 -> h~-tile (w-4).
// Weights held as bf16 MFMA B-fragments in VGPRs (96 VGPRs/lane).

#define Bb 128
#define Tt 1024
#define Ii 256
#define Hh 512
#define HB_PAR (8 * 16 * 256)  // u32 words per h-buffer parity (8 clusters x 16 batches x 256 bf16-pairs)

typedef short short8 __attribute__((ext_vector_type(8)));
typedef float float4_ __attribute__((ext_vector_type(4)));
typedef unsigned int uint4_ __attribute__((ext_vector_type(4)));

__device__ __forceinline__ unsigned short f2bf(float f) {
  union { float f; uint32_t u; } v; v.f = f;
  uint32_t r = v.u + 0x7FFFu + ((v.u >> 16) & 1u);  // RNE
  return (unsigned short)(r >> 16);
}

__global__ void prep_kernel(uint32_t* ws) {
  int i = blockIdx.x * 256 + threadIdx.x;
  if (i < 2 * HB_PAR + 8) ws[i] = 0u;  // zero both h parities + 8 cluster counters
}

__global__ __launch_bounds__(512, 2) void mingru_kernel(
    const float* __restrict__ x, const float* __restrict__ Wz,
    const float* __restrict__ bz, const float* __restrict__ Wh,
    const float* __restrict__ bh, float* __restrict__ out,
    uint32_t* __restrict__ hbuf) {
  uint32_t* cnt = hbuf + 2 * HB_PAR;
  const int bg = blockIdx.x & 7;    // cluster (batch group of 16)
  const int cs = blockIdx.x >> 3;   // column slice (64 H-cols)
  const int tid = threadIdx.x;
  const int wave = tid >> 6;
  const int lane = tid & 63;
  const int lm = lane & 15;
  const int quad = lane >> 4;
  const int is_h = (wave >> 2) & 1; // 0: z-gate (Wz), 1: h~ (Wh)
  const int tile = wave & 3;
  const int wcol = cs * 64 + tile * 16 + lm;  // this lane's B-fragment column
  const float* W = is_h ? Wh : Wz;

  // ---- one-time: load W fragments into registers (bf16) ----
  // B-frag layout (16x16x32): lane holds B[k = quad*8 + j][n = lane&15]
  short8 wx[8], wh[16];
#pragma unroll
  for (int s = 0; s < 8; ++s) {
    union { unsigned short e[8]; short8 v; } u;
#pragma unroll
    for (int j = 0; j < 8; ++j)
      u.e[j] = f2bf(W[(size_t)(s * 32 + quad * 8 + j) * Hh + wcol]);
    wx[s] = u.v;
  }
#pragma unroll
  for (int s = 0; s < 16; ++s) {
    union { unsigned short e[8]; short8 v; } u;
#pragma unroll
    for (int j = 0; j < 8; ++j)
      u.e[j] = f2bf(W[(size_t)(Ii + s * 32 + quad * 8 + j) * Hh + wcol]);
    wh[s] = u.v;
  }

  __shared__ uint32_t hs[16 * 260];   // staged h_{t-1}, bf16 pairs, padded rows (16B-aligned frags)
  __shared__ float S[2][16][66];      // pre-activation z / h~ tiles
  __shared__ int sdead;
  if (tid == 0) sdead = 0;

  // ---- epilogue assignment: lane owns (m = tid>>5, cols ec, ec+1) every step ----
  const int em = tid >> 5;
  const int ec = (tid & 31) << 1;
  const int ecolg = cs * 64 + ec;
  const int eb = bg * 16 + em;
  const float bz0 = bz[ecolg], bz1 = bz[ecolg + 1];
  const float bh0 = bh[ecolg], bh1 = bh[ecolg + 1];
  float hp0 = 0.f, hp1 = 0.f;  // fp32 h state lives in registers across all steps
  float* outp = out + (size_t)eb * (Tt * Hh) + ecolg;
  const uint32_t epair = (uint32_t)((bg * 16 + em) * 256 + (ecolg >> 1));

  const float* xlane = x + (size_t)(bg * 16 + lm) * (Tt * Ii) + quad * 8;

  __syncthreads();

  for (int t = 0; t < Tt; ++t) {
    // ---- x-part: loads + MFMAs, independent of recurrence (hidden under wait) ----
    float4_ acc = {0.f, 0.f, 0.f, 0.f};
    {
      const float* xp = xlane + (size_t)t * Ii;
#pragma unroll
      for (int s = 0; s < 8; ++s) {
        float4_ a0 = *(const float4_*)(xp + 32 * s);
        float4_ a1 = *(const float4_*)(xp + 32 * s + 4);
        union { unsigned short e[8]; short8 v; } u;
        u.e[0] = f2bf(a0[0]); u.e[1] = f2bf(a0[1]);
        u.e[2] = f2bf(a0[2]); u.e[3] = f2bf(a0[3]);
        u.e[4] = f2bf(a1[0]); u.e[5] = f2bf(a1[1]);
        u.e[6] = f2bf(a1[2]); u.e[7] = f2bf(a1[3]);
        acc = __builtin_amdgcn_mfma_f32_16x16x32_bf16(u.v, wx[s], acc, 0, 0, 0);
      }
    }

    // ---- wait for all 8 WGs of this cluster to publish h_{t-1} ----
    if (t > 0) {
      if (tid == 0) {
        const uint32_t target = (uint32_t)(8 * t);
        int spins = 0;
        while (__hip_atomic_load(cnt + bg, __ATOMIC_ACQUIRE,
                                 __HIP_MEMORY_SCOPE_AGENT) < target) {
          __builtin_amdgcn_s_sleep(1);
          if (++spins > (1 << 24)) { sdead = 1; break; }  // fail visibly, never hang
        }
      }
      __syncthreads();
      if (sdead) return;
    }

    // ---- cooperatively stage h_{t-1} (16 x 512 bf16) into LDS ----
    {
      unsigned long long* hq =
          (unsigned long long*)(hbuf + (t & 1) * HB_PAR) + (size_t)bg * 2048;
#pragma unroll
      for (int k = 0; k < 4; ++k) {
        int g = tid + 512 * k;              // u64 index in cluster slice
        unsigned long long v = __hip_atomic_load(hq + g, __ATOMIC_RELAXED,
                                                 __HIP_MEMORY_SCOPE_AGENT);
        int m = g >> 7, c = g & 127;
        *(unsigned long long*)&hs[m * 260 + c * 2] = v;
      }
    }
    __syncthreads();

    // ---- h-part MFMAs: A-frag = h[m = lane&15][k = 32s + quad*8 + j] ----
#pragma unroll
    for (int s = 0; s < 16; ++s) {
      uint4_ d = *(const uint4_*)&hs[lm * 260 + s * 16 + quad * 4];  // 16B aligned
      union { uint4_ q; short8 v; } u; u.q = d;
      acc = __builtin_amdgcn_mfma_f32_16x16x32_bf16(u.v, wh[s], acc, 0, 0, 0);
    }

    // ---- pair z / h~ tiles via LDS (C/D: row = quad*4+r, col = lane&15) ----
    S[is_h][quad * 4 + 0][tile * 16 + lm] = acc[0];
    S[is_h][quad * 4 + 1][tile * 16 + lm] = acc[1];
    S[is_h][quad * 4 + 2][tile * 16 + lm] = acc[2];
    S[is_h][quad * 4 + 3][tile * 16 + lm] = acc[3];
    __syncthreads();

    // ---- epilogue: gates in fp32, update register-resident h ----
    float sz0 = S[0][em][ec]     + bz0;
    float sz1 = S[0][em][ec + 1] + bz1;
    float sh0 = S[1][em][ec]     + bh0;
    float sh1 = S[1][em][ec + 1] + bh1;
    float z0 = 1.f / (1.f + __expf(-sz0));
    float z1 = 1.f / (1.f + __expf(-sz1));
    float g0 = 1.f - 2.f / (1.f + __expf(2.f * sh0));
    float g1 = 1.f - 2.f / (1.f + __expf(2.f * sh1));
    hp0 += z0 * (g0 - hp0);
    hp1 += z1 * (g1 - hp1);

    // ---- publish h_t (bf16 pair, agent-scope so it's fresh cross-XCD) ----
    uint32_t pk = (uint32_t)f2bf(hp0) | ((uint32_t)f2bf(hp1) << 16);
    __hip_atomic_store(hbuf + ((t + 1) & 1) * HB_PAR + epair, pk,
                       __ATOMIC_RELAXED, __HIP_MEMORY_SCOPE_AGENT);
    __syncthreads();  // drains vmcnt(0): all lanes' h stores complete before signal
    if (tid == 0)
      __hip_atomic_fetch_add(cnt + bg, 1u, __ATOMIC_RELEASE,
                             __HIP_MEMORY_SCOPE_AGENT);

    // ---- output stores AFTER signal: off the inter-WG critical path ----
    float2 ov; ov.x = hp0; ov.y = hp1;
    *(float2*)(outp + (size_t)t * Hh) = ov;
    if (t == Tt - 1)
      *(float2*)(out + (size_t)Bb * Tt * Hh + (size_t)eb * Hh + ecolg) = ov;
  }
}

extern "C" void kernel_launch(void* const* d_in, const int* in_sizes, int n_in,
                              void* d_out, int out_size, void* d_ws, size_t ws_size,
                              hipStream_t stream) {
  const float* x  = (const float*)d_in[0];
  const float* Wz = (const float*)d_in[1];
  const float* bz = (const float*)d_in[2];
  const float* Wh = (const float*)d_in[3];
  const float* bh = (const float*)d_in[4];
  float* out = (float*)d_out;
  uint32_t* hbuf = (uint32_t*)d_ws;  // 2*HB_PAR u32 + 8 counters = ~256 KB

  prep_kernel<<<dim3((2 * HB_PAR + 8 + 255) / 256), dim3(256), 0, stream>>>(hbuf);
  mingru_kernel<<<dim3(64), dim3(512), 0, stream>>>(x, Wz, bz, Wh, bh, out, hbuf);
}

// Round 2
// 7564.762 us; speedup vs baseline: 1.1235x; 1.1235x over previous
//
#include <hip/hip_runtime.h>
#include <stdint.h>

// MinGRU persistent kernel for MI355X (gfx950).  Round 2.
// B=128, T=1024, I=256, H=512.
// 8 clusters (16 batches) x 8 WGs (64 H-cols); 512 threads = 8 waves/WG.
// Weights live in VGPRs as bf16 MFMA B-fragments (96 VGPRs/lane).
// R2 change: all inter-WG sync via RELAXED agent atomics + vmcnt discipline.
// No acquire/release fences in the step loop (R1's buffer_inv/wbl2 per step
// caused 540 GB phantom HBM traffic and ~19.5k cyc/step).

#define Bb 128
#define Tt 1024
#define Ii 256
#define Hh 512
#define HB_PAR (8 * 16 * 256)   // u32 words per parity slot (clusters x batches x bf16-pairs)
#define FLAGS_OFF (2 * HB_PAR)  // u32 offset of flag region in ws
#define NFLAG_W (8 * 8 * 16)    // 8 clusters x 8 col-slices, padded to 64B lines

typedef short short8 __attribute__((ext_vector_type(8)));
typedef float float4_ __attribute__((ext_vector_type(4)));
typedef unsigned int uint4_ __attribute__((ext_vector_type(4)));

__device__ __forceinline__ unsigned short f2bf(float f) {
  union { float f; uint32_t u; } v; v.f = f;
  uint32_t r = v.u + 0x7FFFu + ((v.u >> 16) & 1u);  // RNE
  return (unsigned short)(r >> 16);
}

__global__ void prep_kernel(uint32_t* ws) {
  int i = blockIdx.x * 256 + threadIdx.x;
  if (i < NFLAG_W) ws[FLAGS_OFF + i] = 0u;  // only flags need zeroing (ws is poisoned 0xAA)
}

__global__ __launch_bounds__(512, 2) void mingru_kernel(
    const float* __restrict__ x, const float* __restrict__ Wz,
    const float* __restrict__ bz, const float* __restrict__ Wh,
    const float* __restrict__ bh, float* __restrict__ out,
    uint32_t* __restrict__ hbuf) {
  const int bg = blockIdx.x & 7;    // cluster (batch group of 16)
  const int cs = blockIdx.x >> 3;   // this WG's column slice (64 H-cols)
  const int tid = threadIdx.x;
  const int wave = tid >> 6;
  const int lane = tid & 63;
  const int lm = lane & 15;
  const int quad = lane >> 4;
  const int is_h = (wave >> 2) & 1; // 0: z-gate (Wz), 1: h~ (Wh)
  const int tile = wave & 3;
  const int wcol = cs * 64 + tile * 16 + lm;
  const float* W = is_h ? Wh : Wz;

  // ---- one-time: load W fragments into registers (bf16) ----
  // B-frag (16x16x32): lane holds B[k = quad*8 + j][n = lane&15]
  short8 wx[8], wh[16];
#pragma unroll
  for (int s = 0; s < 8; ++s) {
    union { unsigned short e[8]; short8 v; } u;
#pragma unroll
    for (int j = 0; j < 8; ++j)
      u.e[j] = f2bf(W[(size_t)(s * 32 + quad * 8 + j) * Hh + wcol]);
    wx[s] = u.v;
  }
#pragma unroll
  for (int s = 0; s < 16; ++s) {
    union { unsigned short e[8]; short8 v; } u;
#pragma unroll
    for (int j = 0; j < 8; ++j)
      u.e[j] = f2bf(W[(size_t)(Ii + s * 32 + quad * 8 + j) * Hh + wcol]);
    wh[s] = u.v;
  }

  __shared__ uint32_t hs[16 * 260];  // staged h_{t-1} (bf16 pairs), padded rows
  __shared__ float S[2][16][66];     // pre-activation z / h~ tiles

  // ---- epilogue ownership: lane (m = tid>>5, cols ec,ec+1), fp32 h in regs ----
  const int em = tid >> 5;
  const int ec = (tid & 31) << 1;
  const int ecolg = cs * 64 + ec;
  const int eb = bg * 16 + em;
  const float bz0 = bz[ecolg], bz1 = bz[ecolg + 1];
  const float bh0 = bh[ecolg], bh1 = bh[ecolg + 1];
  float hp0 = 0.f, hp1 = 0.f;
  float* outp = out + (size_t)eb * (Tt * Hh) + ecolg;
  const uint32_t epair = (uint32_t)((bg * 16 + em) * 256 + (ecolg >> 1));

  // flag this thread polls: publisher of the h-words it stages.
  // staging word g = tid + 512k -> col-pair c = g&127 (k-invariant) -> cs = c>>4
  uint32_t* flags = hbuf + FLAGS_OFF;
  const uint32_t* pollp = flags + (size_t)(bg * 8 + ((tid >> 4) & 7)) * 16;
  uint32_t* flagwr = flags + (size_t)(bg * 8 + cs) * 16;

  const float* xlane = x + (size_t)(bg * 16 + lm) * (Tt * Ii) + quad * 8;

  for (int t = 0; t < Tt; ++t) {
    // ---- x-part MFMAs: recurrence-independent, runs in the wait shadow ----
    float4_ acc = {0.f, 0.f, 0.f, 0.f};
    {
      const float* xp = xlane + (size_t)t * Ii;
#pragma unroll
      for (int s = 0; s < 8; ++s) {
        float4_ a0 = *(const float4_*)(xp + 32 * s);
        float4_ a1 = *(const float4_*)(xp + 32 * s + 4);
        union { unsigned short e[8]; short8 v; } u;
        u.e[0] = f2bf(a0[0]); u.e[1] = f2bf(a0[1]);
        u.e[2] = f2bf(a0[2]); u.e[3] = f2bf(a0[3]);
        u.e[4] = f2bf(a1[0]); u.e[5] = f2bf(a1[1]);
        u.e[6] = f2bf(a1[2]); u.e[7] = f2bf(a1[3]);
        acc = __builtin_amdgcn_mfma_f32_16x16x32_bf16(u.v, wx[s], acc, 0, 0, 0);
      }
    }

    if (t > 0) {
      // ---- relaxed poll: wait for the one publisher this thread depends on ----
      int spins = 0;
      while (__hip_atomic_load(pollp, __ATOMIC_RELAXED,
                               __HIP_MEMORY_SCOPE_AGENT) < (uint32_t)t) {
        __builtin_amdgcn_s_sleep(1);
        if (++spins > (1 << 26)) break;  // proceed -> visible wrong answer, never a hang
      }
      // ---- stage h_{t-1} (slot (t-1)&1): 4 u64 relaxed atomic loads/thread ----
      {
        unsigned long long* hq =
            (unsigned long long*)(hbuf + ((t - 1) & 1) * HB_PAR) + (size_t)bg * 2048;
#pragma unroll
        for (int k = 0; k < 4; ++k) {
          int g = tid + 512 * k;
          unsigned long long v = __hip_atomic_load(hq + g, __ATOMIC_RELAXED,
                                                   __HIP_MEMORY_SCOPE_AGENT);
          int m = g >> 7, c = g & 127;
          *(unsigned long long*)&hs[m * 260 + c * 2] = v;
        }
      }
      __syncthreads();

      // ---- h-part MFMAs: A-frag = h[m = lane&15][k = 32s + quad*8 + j] ----
#pragma unroll
      for (int s = 0; s < 16; ++s) {
        uint4_ d = *(const uint4_*)&hs[lm * 260 + s * 16 + quad * 4];
        union { uint4_ q; short8 v; } u; u.q = d;
        acc = __builtin_amdgcn_mfma_f32_16x16x32_bf16(u.v, wh[s], acc, 0, 0, 0);
      }
    }

    // ---- pair z / h~ tiles via LDS (C/D: row = quad*4+r, col = lane&15) ----
    S[is_h][quad * 4 + 0][tile * 16 + lm] = acc[0];
    S[is_h][quad * 4 + 1][tile * 16 + lm] = acc[1];
    S[is_h][quad * 4 + 2][tile * 16 + lm] = acc[2];
    S[is_h][quad * 4 + 3][tile * 16 + lm] = acc[3];
    __syncthreads();

    // ---- epilogue: gates in fp32, update register-resident h ----
    float sz0 = S[0][em][ec]     + bz0;
    float sz1 = S[0][em][ec + 1] + bz1;
    float sh0 = S[1][em][ec]     + bh0;
    float sh1 = S[1][em][ec + 1] + bh1;
    float z0 = 1.f / (1.f + __expf(-sz0));
    float z1 = 1.f / (1.f + __expf(-sz1));
    float g0 = 1.f - 2.f / (1.f + __expf(2.f * sh0));
    float g1 = 1.f - 2.f / (1.f + __expf(2.f * sh1));
    hp0 += z0 * (g0 - hp0);
    hp1 += z1 * (g1 - hp1);

    // ---- publish h_t to slot t&1 (relaxed agent store, cache-bypassing) ----
    uint32_t pk = (uint32_t)f2bf(hp0) | ((uint32_t)f2bf(hp1) << 16);
    __hip_atomic_store(hbuf + (t & 1) * HB_PAR + epair, pk,
                       __ATOMIC_RELAXED, __HIP_MEMORY_SCOPE_AGENT);
    // per-wave drain (store ACKed at coherence point), then WG-wide rendezvous,
    // then a single relaxed flag store.  No wbl2, no inv.
    __builtin_amdgcn_s_waitcnt(0);
    __syncthreads();
    if (tid == 0)
      __hip_atomic_store(flagwr, (uint32_t)(t + 1),
                         __ATOMIC_RELAXED, __HIP_MEMORY_SCOPE_AGENT);

    // ---- output stores AFTER signal: off the inter-WG critical path ----
    float2 ov; ov.x = hp0; ov.y = hp1;
    *(float2*)(outp + (size_t)t * Hh) = ov;
    if (t == Tt - 1)
      *(float2*)(out + (size_t)Bb * Tt * Hh + (size_t)eb * Hh + ecolg) = ov;
  }
}

extern "C" void kernel_launch(void* const* d_in, const int* in_sizes, int n_in,
                              void* d_out, int out_size, void* d_ws, size_t ws_size,
                              hipStream_t stream) {
  const float* x  = (const float*)d_in[0];
  const float* Wz = (const float*)d_in[1];
  const float* bz = (const float*)d_in[2];
  const float* Wh = (const float*)d_in[3];
  const float* bh = (const float*)d_in[4];
  float* out = (float*)d_out;
  uint32_t* hbuf = (uint32_t*)d_ws;  // 2*HB_PAR u32 h-slots + flag region (~260 KB)

  prep_kernel<<<dim3((NFLAG_W + 255) / 256), dim3(256), 0, stream>>>(hbuf);
  mingru_kernel<<<dim3(64), dim3(512), 0, stream>>>(x, Wz, bz, Wh, bh, out, hbuf);
}